// Round 1
// baseline (965.425 us; speedup 1.0000x reference)
//
#include <hip/hip_runtime.h>
#include <stdint.h>

#define WS_ALIGN(x) (((x) + 255) & ~(size_t)255)

// ---------------- index dtype detection ----------------
// If edge_index is int64 (little-endian, values in [0, N) < 2^31), every odd
// 32-bit word is 0. If it was converted to int32, odd words are row[1],row[3],...
// which are ~never all zero over 2048 samples. flagOr==0  =>  int64.
__global__ void detect_idx_kernel(const int* __restrict__ p, int* __restrict__ flagOr) {
    int t = threadIdx.x;
    int v = 0;
    for (int i = t; i < 2048; i += 256) v |= p[2 * i + 1];
    if (v) atomicOr(flagOr, v);
}

// ---------------- degree histogram ----------------
__global__ void hist_kernel(const void* __restrict__ eidx, int E,
                            const int* __restrict__ flagOr, int* __restrict__ cnt) {
    int e = blockIdx.x * 256 + threadIdx.x;
    if (e >= E) return;
    bool is64 = (*flagOr == 0);
    int r = is64 ? (int)((const long long*)eidx)[e] : ((const int*)eidx)[e];
    atomicAdd(&cnt[r], 1);
}

// ---------------- 3-kernel exclusive scan over counts ----------------
__global__ void scan1_kernel(const int* __restrict__ cnt, int* __restrict__ offs,
                             int* __restrict__ bsum, int N) {
    __shared__ int tmp[512];
    int tid = threadIdx.x;
    int i = blockIdx.x * 512 + tid;
    int v = (i < N) ? cnt[i] : 0;
    tmp[tid] = v;
    __syncthreads();
    for (int off = 1; off < 512; off <<= 1) {
        int t = (tid >= off) ? tmp[tid - off] : 0;
        __syncthreads();
        tmp[tid] += t;
        __syncthreads();
    }
    if (i < N) offs[i] = tmp[tid] - v;   // exclusive
    if (tid == 511) bsum[blockIdx.x] = tmp[511];
}

__global__ void scan2_kernel(int* __restrict__ bsum, int nb) {
    if (threadIdx.x == 0 && blockIdx.x == 0) {
        int acc = 0;
        for (int i = 0; i < nb; ++i) { int t = bsum[i]; bsum[i] = acc; acc += t; }
        bsum[nb] = acc;
    }
}

__global__ void scan3_kernel(int* __restrict__ offs, const int* __restrict__ bsum,
                             int N, int nb) {
    int i = blockIdx.x * 512 + threadIdx.x;
    if (i < N) offs[i] += bsum[blockIdx.x];
    if (i == 0) offs[N] = bsum[nb];
}

// ---------------- CSR column fill ----------------
__global__ void fill_kernel(const void* __restrict__ eidx, int E,
                            const int* __restrict__ flagOr,
                            const int* __restrict__ offs, int* __restrict__ cursor,
                            int* __restrict__ csr) {
    int e = blockIdx.x * 256 + threadIdx.x;
    if (e >= E) return;
    bool is64 = (*flagOr == 0);
    int r, c;
    if (is64) {
        const long long* p = (const long long*)eidx;
        r = (int)p[e];
        c = (int)p[E + e];
    } else {
        const int* p = (const int*)eidx;
        r = p[e];
        c = p[E + e];
    }
    int slot = atomicAdd(&cursor[r], 1);
    csr[offs[r] + slot] = c;
}

// ---------------- layer 1: agg/deg + x, @W1+b1, relu -> h [N,128] ----------------
__global__ __launch_bounds__(256) void layer1_kernel(
    const float* __restrict__ x, const float* __restrict__ W1,
    const float* __restrict__ b1, const int* __restrict__ offs,
    const int* __restrict__ csr, float* __restrict__ h, int N) {
    __shared__ float Wl[64 * 128];
    __shared__ float bl[128];
    int tid = threadIdx.x;
    for (int i = tid; i < 64 * 128; i += 256) Wl[i] = W1[i];
    if (tid < 128) bl[tid] = b1[tid];
    __syncthreads();

    int w = tid >> 6, l = tid & 63;
    int n = blockIdx.x * 4 + w;
    if (n >= N) return;

    int s = offs[n], e = offs[n + 1];
    float acc = 0.f;
    for (int idx = s; idx < e; ++idx) {
        int c = csr[idx];                 // wave-uniform -> s_load
        acc += x[c * 64 + l];             // coalesced 256B per neighbor
    }
    float deg = (float)((e - s) > 1 ? (e - s) : 1);
    float v = acc / deg + x[n * 64 + l];

    float o0 = bl[l], o1 = bl[l + 64];
    for (int j = 0; j < 64; ++j) {
        float vj = __shfl(v, j);
        o0 += vj * Wl[j * 128 + l];
        o1 += vj * Wl[j * 128 + 64 + l];
    }
    o0 = fmaxf(o0, 0.f);
    o1 = fmaxf(o1, 0.f);
    h[n * 128 + l] = o0;
    h[n * 128 + 64 + l] = o1;
}

// ---------------- layer 2: agg/deg + h, @W2+b2 -> out [N,64] ----------------
__global__ __launch_bounds__(256) void layer2_kernel(
    const float* __restrict__ h, const float* __restrict__ W2,
    const float* __restrict__ b2, const int* __restrict__ offs,
    const int* __restrict__ csr, float* __restrict__ out, int N) {
    __shared__ float Wl[128 * 64];
    __shared__ float bl[64];
    int tid = threadIdx.x;
    for (int i = tid; i < 128 * 64; i += 256) Wl[i] = W2[i];
    if (tid < 64) bl[tid] = b2[tid];
    __syncthreads();

    int w = tid >> 6, l = tid & 63;
    int n = blockIdx.x * 4 + w;
    if (n >= N) return;

    int s = offs[n], e = offs[n + 1];
    float a0 = 0.f, a1 = 0.f;
    for (int idx = s; idx < e; ++idx) {
        int c = csr[idx];
        a0 += h[c * 128 + l];
        a1 += h[c * 128 + 64 + l];
    }
    float deg = (float)((e - s) > 1 ? (e - s) : 1);
    float v0 = a0 / deg + h[n * 128 + l];
    float v1 = a1 / deg + h[n * 128 + 64 + l];

    float o = bl[l];
    for (int j = 0; j < 64; ++j) {
        float vj = __shfl(v0, j);
        o += vj * Wl[j * 64 + l];
    }
    for (int j = 0; j < 64; ++j) {
        float vj = __shfl(v1, j);
        o += vj * Wl[(64 + j) * 64 + l];
    }
    out[n * 64 + l] = o;
}

extern "C" void kernel_launch(void* const* d_in, const int* in_sizes, int n_in,
                              void* d_out, int out_size, void* d_ws, size_t ws_size,
                              hipStream_t stream) {
    const float* x  = (const float*)d_in[0];
    const void*  ei = d_in[1];
    const float* W1 = (const float*)d_in[2];
    const float* b1 = (const float*)d_in[3];
    const float* W2 = (const float*)d_in[4];
    const float* b2 = (const float*)d_in[5];
    float* out = (float*)d_out;

    int N = out_size / 64;
    int E = in_sizes[1] / 2;
    int nb = (N + 511) / 512;

    // workspace layout
    char* ws = (char*)d_ws;
    size_t off = 0;
    auto alloc = [&](size_t bytes) { size_t r = off; off += WS_ALIGN(bytes); return r; };
    int* flagOr = (int*)(ws + alloc(4));
    int* cnt    = (int*)(ws + alloc((size_t)4 * N));
    int* offs   = (int*)(ws + alloc((size_t)4 * (N + 1)));
    int* cursor = (int*)(ws + alloc((size_t)4 * N));
    int* bsum   = (int*)(ws + alloc((size_t)4 * (nb + 1)));
    int* csr    = (int*)(ws + alloc((size_t)4 * E));
    float* h    = (float*)(ws + alloc((size_t)4 * N * 128));
    (void)ws_size;

    hipMemsetAsync(flagOr, 0, 4, stream);
    hipMemsetAsync(cnt, 0, (size_t)4 * N, stream);
    hipMemsetAsync(cursor, 0, (size_t)4 * N, stream);

    detect_idx_kernel<<<1, 256, 0, stream>>>((const int*)ei, flagOr);
    hist_kernel<<<(E + 255) / 256, 256, 0, stream>>>(ei, E, flagOr, cnt);
    scan1_kernel<<<nb, 512, 0, stream>>>(cnt, offs, bsum, N);
    scan2_kernel<<<1, 64, 0, stream>>>(bsum, nb);
    scan3_kernel<<<nb, 512, 0, stream>>>(offs, bsum, N, nb);
    fill_kernel<<<(E + 255) / 256, 256, 0, stream>>>(ei, E, flagOr, offs, cursor, csr);

    int nblk = (N + 3) / 4;
    layer1_kernel<<<nblk, 256, 0, stream>>>(x, W1, b1, offs, csr, h, N);
    layer2_kernel<<<nblk, 256, 0, stream>>>(h, W2, b2, offs, csr, out, N);
}

// Round 2
// 670.351 us; speedup vs baseline: 1.4402x; 1.4402x over previous
//
#include <hip/hip_runtime.h>
#include <stdint.h>

#define WS_ALIGN(x) (((x) + 255) & ~(size_t)255)

// ---------------- index dtype detection ----------------
// int64 little-endian with values < 2^31  =>  every odd 32-bit word is 0.
__global__ void detect_idx_kernel(const int* __restrict__ p, int* __restrict__ flagOr) {
    int t = threadIdx.x;
    int v = 0;
    for (int i = t; i < 2048; i += 256) v |= p[2 * i + 1];
    if (v) atomicOr(flagOr, v);
}

// ---------------- degree histogram ----------------
__global__ void hist_kernel(const void* __restrict__ eidx, int E,
                            const int* __restrict__ flagOr, int* __restrict__ cnt) {
    int e = blockIdx.x * 256 + threadIdx.x;
    if (e >= E) return;
    bool is64 = (*flagOr == 0);
    int r = is64 ? (int)((const long long*)eidx)[e] : ((const int*)eidx)[e];
    atomicAdd(&cnt[r], 1);
}

// ---------------- 3-kernel exclusive scan over counts ----------------
__global__ void scan1_kernel(const int* __restrict__ cnt, int* __restrict__ offs,
                             int* __restrict__ bsum, int N) {
    __shared__ int tmp[512];
    int tid = threadIdx.x;
    int i = blockIdx.x * 512 + tid;
    int v = (i < N) ? cnt[i] : 0;
    tmp[tid] = v;
    __syncthreads();
    for (int off = 1; off < 512; off <<= 1) {
        int t = (tid >= off) ? tmp[tid - off] : 0;
        __syncthreads();
        tmp[tid] += t;
        __syncthreads();
    }
    if (i < N) offs[i] = tmp[tid] - v;   // exclusive
    if (tid == 511) bsum[blockIdx.x] = tmp[511];
}

__global__ void scan2_kernel(int* __restrict__ bsum, int nb) {
    if (threadIdx.x == 0 && blockIdx.x == 0) {
        int acc = 0;
        for (int i = 0; i < nb; ++i) { int t = bsum[i]; bsum[i] = acc; acc += t; }
        bsum[nb] = acc;
    }
}

__global__ void scan3_kernel(int* __restrict__ offs, const int* __restrict__ bsum,
                             int N, int nb) {
    int i = blockIdx.x * 512 + threadIdx.x;
    if (i < N) offs[i] += bsum[blockIdx.x];
    if (i == 0) offs[N] = bsum[nb];
}

// ---------------- CSR column fill ----------------
__global__ void fill_kernel(const void* __restrict__ eidx, int E,
                            const int* __restrict__ flagOr,
                            const int* __restrict__ offs, int* __restrict__ cursor,
                            int* __restrict__ csr) {
    int e = blockIdx.x * 256 + threadIdx.x;
    if (e >= E) return;
    bool is64 = (*flagOr == 0);
    int r, c;
    if (is64) {
        const long long* p = (const long long*)eidx;
        r = (int)p[e];
        c = (int)p[E + e];
    } else {
        const int* p = (const int*)eidx;
        r = p[e];
        c = p[E + e];
    }
    int slot = atomicAdd(&cursor[r], 1);
    csr[offs[r] + slot] = c;
}

// ---------------- fused layer1 + W2 transform ----------------
// v = agg(x)/deg + x_self            (64-d, gather)
// h = relu(v @ W1 + b1)              (128-d, in registers: o0,o1)
// g = h @ W2                         (64-d)  [b2 added in finish kernel]
// LDS: W1 (32 KB) + W2 (32 KB) = 64 KB exactly -> 2 blocks/CU with 1024-thr
// blocks = 32 waves/CU. Biases read from global (L1-resident).
__global__ __launch_bounds__(1024, 8) void layer1_fused_kernel(
    const float* __restrict__ x, const float* __restrict__ W1,
    const float* __restrict__ b1, const float* __restrict__ W2,
    const int* __restrict__ offs, const int* __restrict__ csr,
    float* __restrict__ g, int N) {
    __shared__ float W1s[64 * 128];
    __shared__ float W2s[128 * 64];
    int tid = threadIdx.x;
    for (int i = tid; i < 64 * 128; i += 1024) W1s[i] = W1[i];
    for (int i = tid; i < 128 * 64; i += 1024) W2s[i] = W2[i];
    __syncthreads();

    int w = tid >> 6, l = tid & 63;
    int n = blockIdx.x * 16 + w;
    if (n >= N) return;

    int s = offs[n], e = offs[n + 1];
    float a0 = 0.f, a1 = 0.f, a2 = 0.f, a3 = 0.f;
    int idx = s;
    for (; idx + 3 < e; idx += 4) {
        int c0 = csr[idx], c1 = csr[idx + 1], c2 = csr[idx + 2], c3 = csr[idx + 3];
        a0 += x[(size_t)c0 * 64 + l];
        a1 += x[(size_t)c1 * 64 + l];
        a2 += x[(size_t)c2 * 64 + l];
        a3 += x[(size_t)c3 * 64 + l];
    }
    for (; idx < e; ++idx) a0 += x[(size_t)csr[idx] * 64 + l];
    float acc = (a0 + a1) + (a2 + a3);

    float deg = (float)((e - s) > 1 ? (e - s) : 1);
    float v = acc / deg + x[(size_t)n * 64 + l];

    // h = relu(v @ W1 + b1) : lane l holds h[l] (o0) and h[l+64] (o1)
    float o0 = b1[l], o1 = b1[l + 64];
    #pragma unroll 8
    for (int j = 0; j < 64; ++j) {
        float vj = __shfl(v, j);
        o0 += vj * W1s[j * 128 + l];
        o1 += vj * W1s[j * 128 + 64 + l];
    }
    o0 = fmaxf(o0, 0.f);
    o1 = fmaxf(o1, 0.f);

    // g = h @ W2 : lane l computes g[l]
    float gl = 0.f;
    #pragma unroll 8
    for (int j = 0; j < 64; ++j) {
        float hj = __shfl(o0, j);
        gl += hj * W2s[j * 64 + l];
    }
    #pragma unroll 8
    for (int j = 0; j < 64; ++j) {
        float hj = __shfl(o1, j);
        gl += hj * W2s[(64 + j) * 64 + l];
    }
    g[(size_t)n * 64 + l] = gl;
}

// ---------------- layer2 finish: out = agg(g)/deg + g_self + b2 ----------------
// No weights, no LDS -> full occupancy; pure 64-d gather.
__global__ __launch_bounds__(256) void layer2_finish_kernel(
    const float* __restrict__ g, const float* __restrict__ b2,
    const int* __restrict__ offs, const int* __restrict__ csr,
    float* __restrict__ out, int N) {
    int tid = threadIdx.x;
    int w = tid >> 6, l = tid & 63;
    int n = blockIdx.x * 4 + w;
    if (n >= N) return;

    int s = offs[n], e = offs[n + 1];
    float a0 = 0.f, a1 = 0.f, a2 = 0.f, a3 = 0.f;
    int idx = s;
    for (; idx + 3 < e; idx += 4) {
        int c0 = csr[idx], c1 = csr[idx + 1], c2 = csr[idx + 2], c3 = csr[idx + 3];
        a0 += g[(size_t)c0 * 64 + l];
        a1 += g[(size_t)c1 * 64 + l];
        a2 += g[(size_t)c2 * 64 + l];
        a3 += g[(size_t)c3 * 64 + l];
    }
    for (; idx < e; ++idx) a0 += g[(size_t)csr[idx] * 64 + l];
    float acc = (a0 + a1) + (a2 + a3);

    float deg = (float)((e - s) > 1 ? (e - s) : 1);
    out[(size_t)n * 64 + l] = acc / deg + g[(size_t)n * 64 + l] + b2[l];
}

extern "C" void kernel_launch(void* const* d_in, const int* in_sizes, int n_in,
                              void* d_out, int out_size, void* d_ws, size_t ws_size,
                              hipStream_t stream) {
    const float* x  = (const float*)d_in[0];
    const void*  ei = d_in[1];
    const float* W1 = (const float*)d_in[2];
    const float* b1 = (const float*)d_in[3];
    const float* W2 = (const float*)d_in[4];
    const float* b2 = (const float*)d_in[5];
    float* out = (float*)d_out;

    int N = out_size / 64;
    int E = in_sizes[1] / 2;
    int nb = (N + 511) / 512;

    // workspace layout
    char* ws = (char*)d_ws;
    size_t off = 0;
    auto alloc = [&](size_t bytes) { size_t r = off; off += WS_ALIGN(bytes); return r; };
    int* flagOr = (int*)(ws + alloc(4));
    int* cnt    = (int*)(ws + alloc((size_t)4 * N));
    int* offs   = (int*)(ws + alloc((size_t)4 * (N + 1)));
    int* cursor = (int*)(ws + alloc((size_t)4 * N));
    int* bsum   = (int*)(ws + alloc((size_t)4 * (nb + 1)));
    int* csr    = (int*)(ws + alloc((size_t)4 * E));
    float* g    = (float*)(ws + alloc((size_t)4 * N * 64));
    (void)ws_size;

    hipMemsetAsync(flagOr, 0, 4, stream);
    hipMemsetAsync(cnt, 0, (size_t)4 * N, stream);
    hipMemsetAsync(cursor, 0, (size_t)4 * N, stream);

    detect_idx_kernel<<<1, 256, 0, stream>>>((const int*)ei, flagOr);
    hist_kernel<<<(E + 255) / 256, 256, 0, stream>>>(ei, E, flagOr, cnt);
    scan1_kernel<<<nb, 512, 0, stream>>>(cnt, offs, bsum, N);
    scan2_kernel<<<1, 64, 0, stream>>>(bsum, nb);
    scan3_kernel<<<nb, 512, 0, stream>>>(offs, bsum, N, nb);
    fill_kernel<<<(E + 255) / 256, 256, 0, stream>>>(ei, E, flagOr, offs, cursor, csr);

    layer1_fused_kernel<<<(N + 15) / 16, 1024, 0, stream>>>(x, W1, b1, W2, offs, csr, g, N);
    layer2_finish_kernel<<<(N + 3) / 4, 256, 0, stream>>>(g, b2, offs, csr, out, N);
}

// Round 3
// 492.529 us; speedup vs baseline: 1.9601x; 1.3610x over previous
//
#include <hip/hip_runtime.h>
#include <stdint.h>

#define WS_ALIGN(x) (((x) + 255) & ~(size_t)255)

typedef __attribute__((ext_vector_type(8))) unsigned short ushort8_t;

static __device__ __forceinline__ unsigned short f2bf(float f) {
    unsigned u = __float_as_uint(f);
    unsigned r = (u + 0x7FFFu + ((u >> 16) & 1u)) >> 16;   // RNE
    return (unsigned short)r;
}
static __device__ __forceinline__ float bf2f(unsigned short s) {
    return __uint_as_float(((unsigned)s) << 16);
}

// ---------------- index dtype detection ----------------
__global__ void detect_idx_kernel(const int* __restrict__ p, int* __restrict__ flagOr) {
    int t = threadIdx.x;
    int v = 0;
    for (int i = t; i < 2048; i += 256) v |= p[2 * i + 1];
    if (v) atomicOr(flagOr, v);
}

// ---------------- degree histogram ----------------
__global__ void hist_kernel(const void* __restrict__ eidx, int E,
                            const int* __restrict__ flagOr, int* __restrict__ cnt) {
    int e = blockIdx.x * 256 + threadIdx.x;
    if (e >= E) return;
    bool is64 = (*flagOr == 0);
    int r = is64 ? (int)((const long long*)eidx)[e] : ((const int*)eidx)[e];
    atomicAdd(&cnt[r], 1);
}

// ---------------- 3-kernel exclusive scan over counts ----------------
__global__ void scan1_kernel(const int* __restrict__ cnt, int* __restrict__ offs,
                             int* __restrict__ bsum, int N) {
    __shared__ int tmp[512];
    int tid = threadIdx.x;
    int i = blockIdx.x * 512 + tid;
    int v = (i < N) ? cnt[i] : 0;
    tmp[tid] = v;
    __syncthreads();
    for (int off = 1; off < 512; off <<= 1) {
        int t = (tid >= off) ? tmp[tid - off] : 0;
        __syncthreads();
        tmp[tid] += t;
        __syncthreads();
    }
    if (i < N) offs[i] = tmp[tid] - v;   // exclusive
    if (tid == 511) bsum[blockIdx.x] = tmp[511];
}

__global__ void scan2_kernel(int* __restrict__ bsum, int nb) {
    if (threadIdx.x == 0 && blockIdx.x == 0) {
        int acc = 0;
        for (int i = 0; i < nb; ++i) { int t = bsum[i]; bsum[i] = acc; acc += t; }
        bsum[nb] = acc;
    }
}

__global__ void scan3_kernel(int* __restrict__ offs, const int* __restrict__ bsum,
                             int N, int nb) {
    int i = blockIdx.x * 512 + threadIdx.x;
    if (i < N) offs[i] += bsum[blockIdx.x];
    if (i == 0) offs[N] = bsum[nb];
}

// ---------------- CSR column fill ----------------
__global__ void fill_kernel(const void* __restrict__ eidx, int E,
                            const int* __restrict__ flagOr,
                            const int* __restrict__ offs, int* __restrict__ cursor,
                            int* __restrict__ csr) {
    int e = blockIdx.x * 256 + threadIdx.x;
    if (e >= E) return;
    bool is64 = (*flagOr == 0);
    int r, c;
    if (is64) {
        const long long* p = (const long long*)eidx;
        r = (int)p[e];
        c = (int)p[E + e];
    } else {
        const int* p = (const int*)eidx;
        r = p[e];
        c = p[E + e];
    }
    int slot = atomicAdd(&cursor[r], 1);
    csr[offs[r] + slot] = c;
}

// ---------------- agg: v = agg(x)/deg + x_self  (bf16 out) ----------------
// One wave per node, lane = feature. No LDS -> full occupancy; unroll 8 for MLP.
__global__ __launch_bounds__(256) void agg_kernel(
    const float* __restrict__ x, const int* __restrict__ offs,
    const int* __restrict__ csr, unsigned short* __restrict__ v, int N) {
    int tid = threadIdx.x;
    int w = tid >> 6, l = tid & 63;
    int n = blockIdx.x * 4 + w;
    if (n >= N) return;
    int s = offs[n], e = offs[n + 1];
    float xself = x[(size_t)n * 64 + l];
    float a0 = 0, a1 = 0, a2 = 0, a3 = 0, a4 = 0, a5 = 0, a6 = 0, a7 = 0;
    int idx = s;
    for (; idx + 7 < e; idx += 8) {
        int c0 = csr[idx],     c1 = csr[idx + 1], c2 = csr[idx + 2], c3 = csr[idx + 3];
        int c4 = csr[idx + 4], c5 = csr[idx + 5], c6 = csr[idx + 6], c7 = csr[idx + 7];
        a0 += x[(size_t)c0 * 64 + l]; a1 += x[(size_t)c1 * 64 + l];
        a2 += x[(size_t)c2 * 64 + l]; a3 += x[(size_t)c3 * 64 + l];
        a4 += x[(size_t)c4 * 64 + l]; a5 += x[(size_t)c5 * 64 + l];
        a6 += x[(size_t)c6 * 64 + l]; a7 += x[(size_t)c7 * 64 + l];
    }
    for (; idx < e; ++idx) a0 += x[(size_t)csr[idx] * 64 + l];
    float acc = ((a0 + a1) + (a2 + a3)) + ((a4 + a5) + (a6 + a7));
    float deg = (float)((e - s) > 1 ? (e - s) : 1);
    float val = acc / deg + xself;
    v[(size_t)n * 64 + l] = f2bf(val);
}

// ---------------- GEMM1: h = relu(v @ W1 + b1), bf16 in/out ----------------
// 64 nodes per 256-thr block; thread computes 8 rows x 4 cols.
__global__ __launch_bounds__(256) void gemm1_kernel(
    const unsigned short* __restrict__ v, const float* __restrict__ W1,
    const float* __restrict__ b1, unsigned short* __restrict__ h, int N) {
    __shared__ unsigned short vsT[64][72];   // [k][node], pad to kill conflicts
    __shared__ float W1s[64 * 128];
    __shared__ float b1s[128];
    int t = threadIdx.x;
    int node0 = blockIdx.x * 64;

    for (int i = t; i < 2048; i += 256)
        ((float4*)W1s)[i] = ((const float4*)W1)[i];
    if (t < 128) b1s[t] = b1[t];
    for (int i = t; i < 1024; i += 256) {
        int node = i >> 4, k0 = (i & 15) * 4;
        int gn = node0 + node;
        ushort4 val = make_ushort4(0, 0, 0, 0);
        if (gn < N) val = *(const ushort4*)&v[(size_t)gn * 64 + k0];
        vsT[k0][node] = val.x; vsT[k0 + 1][node] = val.y;
        vsT[k0 + 2][node] = val.z; vsT[k0 + 3][node] = val.w;
    }
    __syncthreads();

    int ct = t & 31, rt = t >> 5;
    int c0 = ct * 4, r0 = rt * 8;
    float acc[8][4] = {};
    #pragma unroll 4
    for (int k = 0; k < 64; ++k) {
        ushort8_t av = *(const ushort8_t*)&vsT[k][r0];
        float af[8];
        #pragma unroll
        for (int j = 0; j < 8; ++j) af[j] = bf2f(av[j]);
        float4 bv = *(const float4*)&W1s[k * 128 + c0];
        float bf[4] = {bv.x, bv.y, bv.z, bv.w};
        #pragma unroll
        for (int r = 0; r < 8; ++r)
            #pragma unroll
            for (int c = 0; c < 4; ++c)
                acc[r][c] = fmaf(af[r], bf[c], acc[r][c]);
    }
    #pragma unroll
    for (int r = 0; r < 8; ++r) {
        int gn = node0 + r0 + r;
        if (gn < N) {
            ushort4 o;
            o.x = f2bf(fmaxf(acc[r][0] + b1s[c0 + 0], 0.f));
            o.y = f2bf(fmaxf(acc[r][1] + b1s[c0 + 1], 0.f));
            o.z = f2bf(fmaxf(acc[r][2] + b1s[c0 + 2], 0.f));
            o.w = f2bf(fmaxf(acc[r][3] + b1s[c0 + 3], 0.f));
            *(ushort4*)&h[(size_t)gn * 128 + c0] = o;
        }
    }
}

// ---------------- GEMM2: g = h @ W2 (f32 out, b2 added later) ----------------
// 128 nodes per 256-thr block; thread computes 8 rows x 4 cols.
__global__ __launch_bounds__(256) void gemm2_kernel(
    const unsigned short* __restrict__ h, const float* __restrict__ W2,
    float* __restrict__ g, int N) {
    __shared__ unsigned short hT[128][136];  // [k][node]
    __shared__ float W2s[128 * 64];
    int t = threadIdx.x;
    int node0 = blockIdx.x * 128;

    for (int i = t; i < 2048; i += 256)
        ((float4*)W2s)[i] = ((const float4*)W2)[i];
    for (int i = t; i < 4096; i += 256) {
        int node = i >> 5, k0 = (i & 31) * 4;
        int gn = node0 + node;
        ushort4 val = make_ushort4(0, 0, 0, 0);
        if (gn < N) val = *(const ushort4*)&h[(size_t)gn * 128 + k0];
        hT[k0][node] = val.x; hT[k0 + 1][node] = val.y;
        hT[k0 + 2][node] = val.z; hT[k0 + 3][node] = val.w;
    }
    __syncthreads();

    int ct = t & 15, rt = t >> 4;
    int c0 = ct * 4, r0 = rt * 8;
    float acc[8][4] = {};
    #pragma unroll 4
    for (int k = 0; k < 128; ++k) {
        ushort8_t av = *(const ushort8_t*)&hT[k][r0];
        float af[8];
        #pragma unroll
        for (int j = 0; j < 8; ++j) af[j] = bf2f(av[j]);
        float4 bv = *(const float4*)&W2s[k * 64 + c0];
        float bf[4] = {bv.x, bv.y, bv.z, bv.w};
        #pragma unroll
        for (int r = 0; r < 8; ++r)
            #pragma unroll
            for (int c = 0; c < 4; ++c)
                acc[r][c] = fmaf(af[r], bf[c], acc[r][c]);
    }
    #pragma unroll
    for (int r = 0; r < 8; ++r) {
        int gn = node0 + r0 + r;
        if (gn < N) {
            float4 o = make_float4(acc[r][0], acc[r][1], acc[r][2], acc[r][3]);
            *(float4*)&g[(size_t)gn * 64 + c0] = o;
        }
    }
}

// ---------------- final: out = agg(g)/deg + g_self + b2 ----------------
__global__ __launch_bounds__(256) void final_kernel(
    const float* __restrict__ g, const float* __restrict__ b2,
    const int* __restrict__ offs, const int* __restrict__ csr,
    float* __restrict__ out, int N) {
    int tid = threadIdx.x;
    int w = tid >> 6, l = tid & 63;
    int n = blockIdx.x * 4 + w;
    if (n >= N) return;
    int s = offs[n], e = offs[n + 1];
    float gself = g[(size_t)n * 64 + l];
    float bias = b2[l];
    float a0 = 0, a1 = 0, a2 = 0, a3 = 0, a4 = 0, a5 = 0, a6 = 0, a7 = 0;
    int idx = s;
    for (; idx + 7 < e; idx += 8) {
        int c0 = csr[idx],     c1 = csr[idx + 1], c2 = csr[idx + 2], c3 = csr[idx + 3];
        int c4 = csr[idx + 4], c5 = csr[idx + 5], c6 = csr[idx + 6], c7 = csr[idx + 7];
        a0 += g[(size_t)c0 * 64 + l]; a1 += g[(size_t)c1 * 64 + l];
        a2 += g[(size_t)c2 * 64 + l]; a3 += g[(size_t)c3 * 64 + l];
        a4 += g[(size_t)c4 * 64 + l]; a5 += g[(size_t)c5 * 64 + l];
        a6 += g[(size_t)c6 * 64 + l]; a7 += g[(size_t)c7 * 64 + l];
    }
    for (; idx < e; ++idx) a0 += g[(size_t)csr[idx] * 64 + l];
    float acc = ((a0 + a1) + (a2 + a3)) + ((a4 + a5) + (a6 + a7));
    float deg = (float)((e - s) > 1 ? (e - s) : 1);
    out[(size_t)n * 64 + l] = acc / deg + gself + bias;
}

extern "C" void kernel_launch(void* const* d_in, const int* in_sizes, int n_in,
                              void* d_out, int out_size, void* d_ws, size_t ws_size,
                              hipStream_t stream) {
    const float* x  = (const float*)d_in[0];
    const void*  ei = d_in[1];
    const float* W1 = (const float*)d_in[2];
    const float* b1 = (const float*)d_in[3];
    const float* W2 = (const float*)d_in[4];
    const float* b2 = (const float*)d_in[5];
    float* out = (float*)d_out;

    int N = out_size / 64;
    int E = in_sizes[1] / 2;
    int nb = (N + 511) / 512;

    // workspace layout (g overlays v: v dead before gemm2 writes g)
    char* ws = (char*)d_ws;
    size_t off = 0;
    auto alloc = [&](size_t bytes) { size_t r = off; off += WS_ALIGN(bytes); return r; };
    int* flagOr = (int*)(ws + alloc(4));
    int* cnt    = (int*)(ws + alloc((size_t)4 * N));
    int* offs   = (int*)(ws + alloc((size_t)4 * (N + 1)));
    int* cursor = (int*)(ws + alloc((size_t)4 * N));
    int* bsum   = (int*)(ws + alloc((size_t)4 * (nb + 1)));
    int* csr    = (int*)(ws + alloc((size_t)4 * E));
    char* vg    = ws + alloc((size_t)256 * N);          // v: bf16 N*64 | g: f32 N*64
    unsigned short* v = (unsigned short*)vg;
    float*          g = (float*)vg;
    unsigned short* h = (unsigned short*)(ws + alloc((size_t)256 * N)); // bf16 N*128
    (void)ws_size;

    hipMemsetAsync(flagOr, 0, 4, stream);
    hipMemsetAsync(cnt, 0, (size_t)4 * N, stream);
    hipMemsetAsync(cursor, 0, (size_t)4 * N, stream);

    detect_idx_kernel<<<1, 256, 0, stream>>>((const int*)ei, flagOr);
    hist_kernel<<<(E + 255) / 256, 256, 0, stream>>>(ei, E, flagOr, cnt);
    scan1_kernel<<<nb, 512, 0, stream>>>(cnt, offs, bsum, N);
    scan2_kernel<<<1, 64, 0, stream>>>(bsum, nb);
    scan3_kernel<<<nb, 512, 0, stream>>>(offs, bsum, N, nb);
    fill_kernel<<<(E + 255) / 256, 256, 0, stream>>>(ei, E, flagOr, offs, cursor, csr);

    agg_kernel<<<(N + 3) / 4, 256, 0, stream>>>(x, offs, csr, v, N);
    gemm1_kernel<<<(N + 63) / 64, 256, 0, stream>>>(v, W1, b1, h, N);
    gemm2_kernel<<<(N + 127) / 128, 256, 0, stream>>>(h, W2, g, N);
    final_kernel<<<(N + 3) / 4, 256, 0, stream>>>(g, b2, offs, csr, out, N);
}

// Round 4
// 482.442 us; speedup vs baseline: 2.0011x; 1.0209x over previous
//
#include <hip/hip_runtime.h>
#include <stdint.h>

#define WS_ALIGN(x) (((x) + 255) & ~(size_t)255)

typedef __attribute__((ext_vector_type(8))) unsigned short ushort8_t;

static __device__ __forceinline__ unsigned short f2bf(float f) {
    unsigned u = __float_as_uint(f);
    unsigned r = (u + 0x7FFFu + ((u >> 16) & 1u)) >> 16;   // RNE
    return (unsigned short)r;
}
static __device__ __forceinline__ float bf2f(unsigned short s) {
    return __uint_as_float(((unsigned)s) << 16);
}

// ---------------- index dtype detection ----------------
__global__ void detect_idx_kernel(const int* __restrict__ p, int* __restrict__ flagOr) {
    int t = threadIdx.x;
    int v = 0;
    for (int i = t; i < 2048; i += 256) v |= p[2 * i + 1];
    if (v) atomicOr(flagOr, v);
}

// ---------------- degree histogram ----------------
__global__ void hist_kernel(const void* __restrict__ eidx, int E,
                            const int* __restrict__ flagOr, int* __restrict__ cnt) {
    int e = blockIdx.x * 256 + threadIdx.x;
    if (e >= E) return;
    bool is64 = (*flagOr == 0);
    int r = is64 ? (int)((const long long*)eidx)[e] : ((const int*)eidx)[e];
    atomicAdd(&cnt[r], 1);
}

// ---------------- 3-kernel exclusive scan over counts ----------------
__global__ void scan1_kernel(const int* __restrict__ cnt, int* __restrict__ offs,
                             int* __restrict__ bsum, int N) {
    __shared__ int tmp[512];
    int tid = threadIdx.x;
    int i = blockIdx.x * 512 + tid;
    int v = (i < N) ? cnt[i] : 0;
    tmp[tid] = v;
    __syncthreads();
    for (int off = 1; off < 512; off <<= 1) {
        int t = (tid >= off) ? tmp[tid - off] : 0;
        __syncthreads();
        tmp[tid] += t;
        __syncthreads();
    }
    if (i < N) offs[i] = tmp[tid] - v;   // exclusive
    if (tid == 511) bsum[blockIdx.x] = tmp[511];
}

__global__ void scan2_kernel(int* __restrict__ bsum, int nb) {
    if (threadIdx.x == 0 && blockIdx.x == 0) {
        int acc = 0;
        for (int i = 0; i < nb; ++i) { int t = bsum[i]; bsum[i] = acc; acc += t; }
        bsum[nb] = acc;
    }
}

__global__ void scan3_kernel(int* __restrict__ offs, const int* __restrict__ bsum,
                             int N, int nb) {
    int i = blockIdx.x * 512 + threadIdx.x;
    if (i < N) offs[i] += bsum[blockIdx.x];
    if (i == 0) offs[N] = bsum[nb];
}

// ---------------- CSR column fill, row-partitioned pass ----------------
// Only edges with row in [rowLo, rowHi) are scattered this pass, so csr
// writes land in a ~1.6 MB L2-resident window (kills 16x write amplification).
__global__ void fill_pass_kernel(const void* __restrict__ eidx, int E,
                                 const int* __restrict__ flagOr,
                                 const int* __restrict__ offs, int* __restrict__ cursor,
                                 int* __restrict__ csr, int rowLo, int rowHi) {
    int e = blockIdx.x * 256 + threadIdx.x;
    if (e >= E) return;
    bool is64 = (*flagOr == 0);
    int r, c;
    if (is64) {
        const long long* p = (const long long*)eidx;
        r = (int)p[e];
        if (r < rowLo || r >= rowHi) return;
        c = (int)p[E + e];
    } else {
        const int* p = (const int*)eidx;
        r = p[e];
        if (r < rowLo || r >= rowHi) return;
        c = p[E + e];
    }
    int slot = atomicAdd(&cursor[r], 1);
    csr[offs[r] + slot] = c;
}

// ---------------- x -> bf16 copy ----------------
__global__ void xcast_kernel(const float4* __restrict__ x, ushort4* __restrict__ xb,
                             int n4) {
    int i = blockIdx.x * 256 + threadIdx.x;
    if (i >= n4) return;
    float4 f = x[i];
    ushort4 o;
    o.x = f2bf(f.x); o.y = f2bf(f.y); o.z = f2bf(f.z); o.w = f2bf(f.w);
    xb[i] = o;
}

// ---------------- agg: v = agg(xb)/deg + xb_self  (bf16 in/out) ----------------
__global__ __launch_bounds__(256) void agg_kernel(
    const unsigned short* __restrict__ xb, const int* __restrict__ offs,
    const int* __restrict__ csr, unsigned short* __restrict__ v, int N) {
    int tid = threadIdx.x;
    int w = tid >> 6, l = tid & 63;
    int n = blockIdx.x * 4 + w;
    if (n >= N) return;
    int s = offs[n], e = offs[n + 1];
    float xself = bf2f(xb[(size_t)n * 64 + l]);
    float a0 = 0, a1 = 0, a2 = 0, a3 = 0, a4 = 0, a5 = 0, a6 = 0, a7 = 0;
    int idx = s;
    for (; idx + 7 < e; idx += 8) {
        int c0 = csr[idx],     c1 = csr[idx + 1], c2 = csr[idx + 2], c3 = csr[idx + 3];
        int c4 = csr[idx + 4], c5 = csr[idx + 5], c6 = csr[idx + 6], c7 = csr[idx + 7];
        a0 += bf2f(xb[(size_t)c0 * 64 + l]); a1 += bf2f(xb[(size_t)c1 * 64 + l]);
        a2 += bf2f(xb[(size_t)c2 * 64 + l]); a3 += bf2f(xb[(size_t)c3 * 64 + l]);
        a4 += bf2f(xb[(size_t)c4 * 64 + l]); a5 += bf2f(xb[(size_t)c5 * 64 + l]);
        a6 += bf2f(xb[(size_t)c6 * 64 + l]); a7 += bf2f(xb[(size_t)c7 * 64 + l]);
    }
    for (; idx < e; ++idx) a0 += bf2f(xb[(size_t)csr[idx] * 64 + l]);
    float acc = ((a0 + a1) + (a2 + a3)) + ((a4 + a5) + (a6 + a7));
    float deg = (float)((e - s) > 1 ? (e - s) : 1);
    v[(size_t)n * 64 + l] = f2bf(acc / deg + xself);
}

// ---------------- GEMM1: h = relu(v @ W1 + b1), bf16 in/out ----------------
__global__ __launch_bounds__(256) void gemm1_kernel(
    const unsigned short* __restrict__ v, const float* __restrict__ W1,
    const float* __restrict__ b1, unsigned short* __restrict__ h, int N) {
    __shared__ unsigned short vsT[64][72];
    __shared__ float W1s[64 * 128];
    __shared__ float b1s[128];
    int t = threadIdx.x;
    int node0 = blockIdx.x * 64;

    for (int i = t; i < 2048; i += 256)
        ((float4*)W1s)[i] = ((const float4*)W1)[i];
    if (t < 128) b1s[t] = b1[t];
    for (int i = t; i < 1024; i += 256) {
        int node = i >> 4, k0 = (i & 15) * 4;
        int gn = node0 + node;
        ushort4 val = make_ushort4(0, 0, 0, 0);
        if (gn < N) val = *(const ushort4*)&v[(size_t)gn * 64 + k0];
        vsT[k0][node] = val.x; vsT[k0 + 1][node] = val.y;
        vsT[k0 + 2][node] = val.z; vsT[k0 + 3][node] = val.w;
    }
    __syncthreads();

    int ct = t & 31, rt = t >> 5;
    int c0 = ct * 4, r0 = rt * 8;
    float acc[8][4] = {};
    #pragma unroll 4
    for (int k = 0; k < 64; ++k) {
        ushort8_t av = *(const ushort8_t*)&vsT[k][r0];
        float af[8];
        #pragma unroll
        for (int j = 0; j < 8; ++j) af[j] = bf2f(av[j]);
        float4 bv = *(const float4*)&W1s[k * 128 + c0];
        float bf[4] = {bv.x, bv.y, bv.z, bv.w};
        #pragma unroll
        for (int r = 0; r < 8; ++r)
            #pragma unroll
            for (int c = 0; c < 4; ++c)
                acc[r][c] = fmaf(af[r], bf[c], acc[r][c]);
    }
    #pragma unroll
    for (int r = 0; r < 8; ++r) {
        int gn = node0 + r0 + r;
        if (gn < N) {
            ushort4 o;
            o.x = f2bf(fmaxf(acc[r][0] + b1s[c0 + 0], 0.f));
            o.y = f2bf(fmaxf(acc[r][1] + b1s[c0 + 1], 0.f));
            o.z = f2bf(fmaxf(acc[r][2] + b1s[c0 + 2], 0.f));
            o.w = f2bf(fmaxf(acc[r][3] + b1s[c0 + 3], 0.f));
            *(ushort4*)&h[(size_t)gn * 128 + c0] = o;
        }
    }
}

// ---------------- GEMM2: g16 = bf16(h @ W2)  (b2 added in final) ----------------
__global__ __launch_bounds__(256) void gemm2_kernel(
    const unsigned short* __restrict__ h, const float* __restrict__ W2,
    unsigned short* __restrict__ g16, int N) {
    __shared__ unsigned short hT[128][136];
    __shared__ float W2s[128 * 64];
    int t = threadIdx.x;
    int node0 = blockIdx.x * 128;

    for (int i = t; i < 2048; i += 256)
        ((float4*)W2s)[i] = ((const float4*)W2)[i];
    for (int i = t; i < 4096; i += 256) {
        int node = i >> 5, k0 = (i & 31) * 4;
        int gn = node0 + node;
        ushort4 val = make_ushort4(0, 0, 0, 0);
        if (gn < N) val = *(const ushort4*)&h[(size_t)gn * 128 + k0];
        hT[k0][node] = val.x; hT[k0 + 1][node] = val.y;
        hT[k0 + 2][node] = val.z; hT[k0 + 3][node] = val.w;
    }
    __syncthreads();

    int ct = t & 15, rt = t >> 4;
    int c0 = ct * 4, r0 = rt * 8;
    float acc[8][4] = {};
    #pragma unroll 4
    for (int k = 0; k < 128; ++k) {
        ushort8_t av = *(const ushort8_t*)&hT[k][r0];
        float af[8];
        #pragma unroll
        for (int j = 0; j < 8; ++j) af[j] = bf2f(av[j]);
        float4 bv = *(const float4*)&W2s[k * 64 + c0];
        float bf[4] = {bv.x, bv.y, bv.z, bv.w};
        #pragma unroll
        for (int r = 0; r < 8; ++r)
            #pragma unroll
            for (int c = 0; c < 4; ++c)
                acc[r][c] = fmaf(af[r], bf[c], acc[r][c]);
    }
    #pragma unroll
    for (int r = 0; r < 8; ++r) {
        int gn = node0 + r0 + r;
        if (gn < N) {
            ushort4 o;
            o.x = f2bf(acc[r][0]); o.y = f2bf(acc[r][1]);
            o.z = f2bf(acc[r][2]); o.w = f2bf(acc[r][3]);
            *(ushort4*)&g16[(size_t)gn * 64 + c0] = o;
        }
    }
}

// ---------------- final: out = agg(g16)/deg + g16_self + b2  (f32 out) ----------------
__global__ __launch_bounds__(256) void final_kernel(
    const unsigned short* __restrict__ g16, const float* __restrict__ b2,
    const int* __restrict__ offs, const int* __restrict__ csr,
    float* __restrict__ out, int N) {
    int tid = threadIdx.x;
    int w = tid >> 6, l = tid & 63;
    int n = blockIdx.x * 4 + w;
    if (n >= N) return;
    int s = offs[n], e = offs[n + 1];
    float gself = bf2f(g16[(size_t)n * 64 + l]);
    float bias = b2[l];
    float a0 = 0, a1 = 0, a2 = 0, a3 = 0, a4 = 0, a5 = 0, a6 = 0, a7 = 0;
    int idx = s;
    for (; idx + 7 < e; idx += 8) {
        int c0 = csr[idx],     c1 = csr[idx + 1], c2 = csr[idx + 2], c3 = csr[idx + 3];
        int c4 = csr[idx + 4], c5 = csr[idx + 5], c6 = csr[idx + 6], c7 = csr[idx + 7];
        a0 += bf2f(g16[(size_t)c0 * 64 + l]); a1 += bf2f(g16[(size_t)c1 * 64 + l]);
        a2 += bf2f(g16[(size_t)c2 * 64 + l]); a3 += bf2f(g16[(size_t)c3 * 64 + l]);
        a4 += bf2f(g16[(size_t)c4 * 64 + l]); a5 += bf2f(g16[(size_t)c5 * 64 + l]);
        a6 += bf2f(g16[(size_t)c6 * 64 + l]); a7 += bf2f(g16[(size_t)c7 * 64 + l]);
    }
    for (; idx < e; ++idx) a0 += bf2f(g16[(size_t)csr[idx] * 64 + l]);
    float acc = ((a0 + a1) + (a2 + a3)) + ((a4 + a5) + (a6 + a7));
    float deg = (float)((e - s) > 1 ? (e - s) : 1);
    out[(size_t)n * 64 + l] = acc / deg + gself + bias;
}

extern "C" void kernel_launch(void* const* d_in, const int* in_sizes, int n_in,
                              void* d_out, int out_size, void* d_ws, size_t ws_size,
                              hipStream_t stream) {
    const float* x  = (const float*)d_in[0];
    const void*  ei = d_in[1];
    const float* W1 = (const float*)d_in[2];
    const float* b1 = (const float*)d_in[3];
    const float* W2 = (const float*)d_in[4];
    const float* b2 = (const float*)d_in[5];
    float* out = (float*)d_out;

    int N = out_size / 64;
    int E = in_sizes[1] / 2;
    int nb = (N + 511) / 512;

    // workspace layout; bufA holds xb (bf16, dead after agg) then g16 overlays it
    char* ws = (char*)d_ws;
    size_t off = 0;
    auto alloc = [&](size_t bytes) { size_t r = off; off += WS_ALIGN(bytes); return r; };
    int* flagOr = (int*)(ws + alloc(4));
    int* cnt    = (int*)(ws + alloc((size_t)4 * N));
    int* offs   = (int*)(ws + alloc((size_t)4 * (N + 1)));
    int* cursor = (int*)(ws + alloc((size_t)4 * N));
    int* bsum   = (int*)(ws + alloc((size_t)4 * (nb + 1)));
    int* csr    = (int*)(ws + alloc((size_t)4 * E));
    char* bufA  = ws + alloc((size_t)128 * N);           // xb bf16 N*64 | g16 bf16 N*64
    unsigned short* xb  = (unsigned short*)bufA;
    unsigned short* g16 = (unsigned short*)bufA;
    unsigned short* v   = (unsigned short*)(ws + alloc((size_t)128 * N)); // bf16 N*64
    unsigned short* h   = (unsigned short*)(ws + alloc((size_t)256 * N)); // bf16 N*128
    (void)ws_size;

    hipMemsetAsync(flagOr, 0, 4, stream);
    hipMemsetAsync(cnt, 0, (size_t)4 * N, stream);
    hipMemsetAsync(cursor, 0, (size_t)4 * N, stream);

    detect_idx_kernel<<<1, 256, 0, stream>>>((const int*)ei, flagOr);
    hist_kernel<<<(E + 255) / 256, 256, 0, stream>>>(ei, E, flagOr, cnt);
    scan1_kernel<<<nb, 512, 0, stream>>>(cnt, offs, bsum, N);
    scan2_kernel<<<1, 64, 0, stream>>>(bsum, nb);
    scan3_kernel<<<nb, 512, 0, stream>>>(offs, bsum, N, nb);

    int eb = (E + 255) / 256;
    int rowRange = (N + 3) / 4;
    for (int p = 0; p < 4; ++p) {
        int lo = p * rowRange;
        int hi = (p == 3) ? N : (lo + rowRange);
        fill_pass_kernel<<<eb, 256, 0, stream>>>(ei, E, flagOr, offs, cursor, csr, lo, hi);
    }

    xcast_kernel<<<(N * 16 + 255) / 256, 256, 0, stream>>>((const float4*)x, (ushort4*)xb, N * 16);
    agg_kernel<<<(N + 3) / 4, 256, 0, stream>>>(xb, offs, csr, v, N);
    gemm1_kernel<<<(N + 63) / 64, 256, 0, stream>>>(v, W1, b1, h, N);
    gemm2_kernel<<<(N + 127) / 128, 256, 0, stream>>>(h, W2, g16, N);
    final_kernel<<<(N + 3) / 4, 256, 0, stream>>>(g16, b2, offs, csr, out, N);
}